// Round 4
// baseline (280.427 us; speedup 1.0000x reference)
//
#include <hip/hip_runtime.h>
#include <hip/hip_bf16.h>
#include <stdint.h>

// Problem constants
static constexpr int Bn = 8, Hn = 20, Sn = 1024, En = 256, D2 = 512, D4 = 1024;
static constexpr int Mall = Bn * Hn * Sn;   // 163840 rows of hist
static constexpr int BS   = Bn * Sn;        // 8192 rows of cur

typedef __attribute__((ext_vector_type(8))) short bf16x8;
typedef __attribute__((ext_vector_type(4))) float f32x4;

__device__ __forceinline__ unsigned short f2bf(float f) {
  unsigned int u = __float_as_uint(f);
  u += 0x7FFFu + ((u >> 16) & 1u);   // RNE
  return (unsigned short)(u >> 16);
}
__device__ __forceinline__ float bf2f(unsigned short u) {
  return __uint_as_float(((unsigned int)u) << 16);
}
__device__ __forceinline__ float sigmoid_fast(float x) {
  return __builtin_amdgcn_rcpf(1.0f + __expf(-x));
}
// pack bf16(lo=a, hi=b) by TRUNCATION in one v_perm_b32
__device__ __forceinline__ unsigned int packbf_trunc(float a, float b) {
  return __builtin_amdgcn_perm(__float_as_uint(b), __float_as_uint(a),
                               0x07060302u);
}
// pack bf16(lo=a, hi=b) with RNE rounding
__device__ __forceinline__ unsigned int packbf_rne(float a, float b) {
  return ((unsigned int)f2bf(b) << 16) | (unsigned int)f2bf(a);
}
__device__ __forceinline__ uint4 pack8_trunc(float4 f0, float4 f1) {
  uint4 p;
  p.x = packbf_trunc(f0.x, f0.y);
  p.y = packbf_trunc(f0.z, f0.w);
  p.z = packbf_trunc(f1.x, f1.y);
  p.w = packbf_trunc(f1.z, f1.w);
  return p;
}

typedef const __attribute__((address_space(1))) void gv_t;
typedef __attribute__((address_space(3))) void lv_t;
__device__ __forceinline__ void gload_lds16(const void* g, void* l) {
  __builtin_amdgcn_global_load_lds((gv_t*)g, (lv_t*)l, 16, 0, 0);
}

// ---------------------------------------------------------------------------
// Kernel: convert the three weight matrices fp32 -> bf16 (each 262144 el)
// ---------------------------------------------------------------------------
__global__ __launch_bounds__(256) void k_convert_weights(
    const float* __restrict__ wc, const float* __restrict__ wh,
    const float* __restrict__ wf,
    unsigned short* __restrict__ wcb, unsigned short* __restrict__ whb,
    unsigned short* __restrict__ wfb) {
  int idx4 = blockIdx.x * 256 + threadIdx.x;      // 0..196607 (x4 elements)
  int a = idx4 >> 16;                             // which array (65536 float4 each)
  int r = idx4 & 65535;
  const float* s = (a == 0) ? wc : (a == 1) ? wh : wf;
  unsigned short* d = (a == 0) ? wcb : (a == 1) ? whb : wfb;
  float4 v = reinterpret_cast<const float4*>(s)[r];
  ushort4 o;
  o.x = f2bf(v.x); o.y = f2bf(v.y); o.z = f2bf(v.z); o.w = f2bf(v.w);
  reinterpret_cast<ushort4*>(d)[r] = o;
}

// ---------------------------------------------------------------------------
// GEMM (B^T form): C[M,512] = A[M,512] (fp32, trunc->bf16) * W[512,512]^T
// MODE 0: epilogue writes c_proj bf16 (+bias). grid=(Mtiles, 4 Nchunks)
// MODE 1 (fallback only): alpha in one kernel, nc looped inside.
// ---------------------------------------------------------------------------
template <int MODE>
__global__ __launch_bounds__(256) void k_gemm_bt(
    const float* __restrict__ A,               // [M][512] fp32
    const unsigned short* __restrict__ Bw,     // [512][512] bf16 (N-major)
    const float* __restrict__ bias,            // [512] fp32 (wc_b / wh_b)
    const unsigned short* __restrict__ cproj,  // MODE1: [8192][512] bf16
    const float* __restrict__ qtw,             // MODE1: [512] fp32
    const float* __restrict__ qtb,             // MODE1: [1] fp32
    unsigned short* __restrict__ cproj_out,    // MODE0 output
    float* __restrict__ alpha_out) {           // MODE1 output [163840]
  __shared__ __align__(16) unsigned char ldsA[128 * 128];
  __shared__ __align__(16) unsigned char ldsB[128 * 128];

  const int tid = threadIdx.x;
  const int lane = tid & 63, wave = tid >> 6;
  const int lrow = lane & 15, lk = lane >> 4;
  const int row0 = blockIdx.x * 128;
  const f32x4 zero4 = {0.f, 0.f, 0.f, 0.f};

  float asum[2][4];
  if (MODE == 1) {
#pragma unroll
    for (int rf = 0; rf < 2; ++rf)
#pragma unroll
      for (int r = 0; r < 4; ++r) asum[rf][r] = 0.f;
  }

  const int nc_begin = (MODE == 0) ? blockIdx.y : 0;
  const int nc_end   = (MODE == 0) ? (int)blockIdx.y + 1 : 4;

  for (int nc = nc_begin; nc < nc_end; ++nc) {
    f32x4 acc[2][8];
#pragma unroll
    for (int rf = 0; rf < 2; ++rf)
#pragma unroll
      for (int cf = 0; cf < 8; ++cf) acc[rf][cf] = zero4;

    for (int kt = 0; kt < 8; ++kt) {
      __syncthreads();
#pragma unroll
      for (int slot = 0; slot < 4; ++slot) {
        int idx = (slot * 256 + tid) * 8;
        int row = idx >> 6, k = idx & 63;
        const float* src = A + (size_t)(row0 + row) * 512 + kt * 64 + k;
        float4 f0 = *reinterpret_cast<const float4*>(src);
        float4 f1 = *reinterpret_cast<const float4*>(src + 4);
        uint4 p = pack8_trunc(f0, f1);
        int off = row * 128 + ((k * 2) ^ ((row & 7) << 4));
        *reinterpret_cast<uint4*>(ldsA + off) = p;
      }
#pragma unroll
      for (int c = 0; c < 4; ++c) {
        int ci = c * 256 + tid;
        int n = ci >> 3, kc = (ci & 7) * 8;
        const unsigned short* src =
            Bw + (size_t)(nc * 128 + n) * 512 + kt * 64 + kc;
        uint4 p = *reinterpret_cast<const uint4*>(src);
        int off = n * 128 + ((kc * 2) ^ ((n & 7) << 4));
        *reinterpret_cast<uint4*>(ldsB + off) = p;
      }
      __syncthreads();
#pragma unroll
      for (int ks = 0; ks < 2; ++ks) {
        int kbyte = ks * 64 + lk * 16;
        bf16x8 af[2];
#pragma unroll
        for (int rf = 0; rf < 2; ++rf) {
          int ar = wave * 32 + rf * 16 + lrow;
          af[rf] = *reinterpret_cast<const bf16x8*>(
              ldsA + ar * 128 + (kbyte ^ ((ar & 7) << 4)));
        }
#pragma unroll
        for (int cf = 0; cf < 8; ++cf) {
          int br = cf * 16 + lrow;
          bf16x8 bf = *reinterpret_cast<const bf16x8*>(
              ldsB + br * 128 + (kbyte ^ ((br & 7) << 4)));
#pragma unroll
          for (int rf = 0; rf < 2; ++rf)
            acc[rf][cf] = __builtin_amdgcn_mfma_f32_16x16x32_bf16(
                af[rf], bf, acc[rf][cf], 0, 0, 0);
        }
      }
    }

    if (MODE == 0) {
#pragma unroll
      for (int cf = 0; cf < 8; ++cf) {
        int e = nc * 128 + cf * 16 + lrow;
        float bse = bias[e];
#pragma unroll
        for (int rf = 0; rf < 2; ++rf)
#pragma unroll
          for (int r = 0; r < 4; ++r) {
            int row = row0 + wave * 32 + rf * 16 + lk * 4 + r;
            cproj_out[(size_t)row * 512 + e] = f2bf(acc[rf][cf][r] + bse);
          }
      }
    } else {
#pragma unroll
      for (int cf = 0; cf < 8; ++cf) {
        int e = nc * 128 + cf * 16 + lrow;
        float whb = bias[e];
        float qw = qtw[e];
#pragma unroll
        for (int rf = 0; rf < 2; ++rf)
#pragma unroll
          for (int r = 0; r < 4; ++r) {
            int row = row0 + wave * 32 + rf * 16 + lk * 4 + r;
            int bsrow = ((row / (Hn * Sn)) << 10) | (row & 1023);
            float cp = bf2f(cproj[(size_t)bsrow * 512 + e]);
            float g = sigmoid_fast(acc[rf][cf][r] + whb + cp);
            asum[rf][r] = fmaf(g, qw, asum[rf][r]);
          }
      }
    }
  }

  if (MODE == 1) {
#pragma unroll
    for (int off = 1; off < 16; off <<= 1) {
#pragma unroll
      for (int rf = 0; rf < 2; ++rf)
#pragma unroll
        for (int r = 0; r < 4; ++r)
          asum[rf][r] += __shfl_xor(asum[rf][r], off, 64);
    }
    if (lrow == 0) {
      float qb = qtb[0];
#pragma unroll
      for (int rf = 0; rf < 2; ++rf)
#pragma unroll
        for (int r = 0; r < 4; ++r) {
          int row = row0 + wave * 32 + rf * 16 + lk * 4 + r;
          alpha_out[row] = asum[rf][r] + qb;
        }
    }
  }
}

// ---------------------------------------------------------------------------
// k_alpha_p: high-TLP alpha GEMM. Tile M=128 x N=256; flat grid 2560 with
// nc = bid&1 so the A-sharing sibling is co-resident (L2/L3 serves the 2nd
// A read -- round-0 evidence: 4x logical A re-read showed no FETCH blowup).
// 512 threads, 48KB LDS -> 2-3 blocks/CU: TLP hides latency (m114), no
// lockstep mega-pipeline. Per kt: [bar] issueB(gload_lds,4) | writeA(pack
// regs->lds) | issueA(kt+1, stays in flight: vmcnt(4)) [bar] compute.
// Epilogue: sigmoid(acc+wh_b+cproj)*qt_w, e-partial -> part[2][163840].
// ---------------------------------------------------------------------------
__global__ __launch_bounds__(512, 4) void k_alpha_p(
    const float* __restrict__ A,               // hist [163840][512] fp32
    const unsigned short* __restrict__ Bw,     // whb [512][512] bf16
    const float* __restrict__ bias,            // wh_b [512]
    const unsigned short* __restrict__ cproj,  // [8192][512] bf16
    const float* __restrict__ qtw,             // [512]
    float* __restrict__ part) {                // [2][163840] fp32
  __shared__ __align__(16) unsigned char ldsA[16384];  // bf16 128x64 swizzled
  __shared__ __align__(16) unsigned char ldsB[32768];  // bf16 256x64 swizzled
  __shared__ float red[2][128];

  const int tid = threadIdx.x;
  const int lane = tid & 63, wave = tid >> 6;
  const int lrow = lane & 15, lk = lane >> 4;
  const int wr = wave & 3, wcc = wave >> 2;
  const int nc = blockIdx.x & 1;
  const int row0 = (blockIdx.x >> 1) * 128;
  const int ncol0 = nc * 256;
  const f32x4 zero4 = {0.f, 0.f, 0.f, 0.f};

  // B global base: lds chunk W covers rows n = W*8 + (lane>>3); slot lane&7
  // holds k-group (lane&7)^(n&7); n&7 = lane>>3 (W*8 == 0 mod 8).
  const int nrl = lane >> 3, nsl = lane & 7;
  const unsigned short* gBb =
      Bw + (size_t)(ncol0 + nrl) * 512 + (nsl ^ nrl) * 8;

  float4 pa[4];
  auto issueA = [&](int kt) {
#pragma unroll
    for (int j = 0; j < 4; ++j) {
      int u = j * 512 + tid;
      int r = u >> 4, c4 = u & 15;
      pa[j] = *reinterpret_cast<const float4*>(
          A + (size_t)(row0 + r) * 512 + kt * 64 + c4 * 4);
    }
  };
  auto writeA = [&]() {
#pragma unroll
    for (int j = 0; j < 4; ++j) {
      int u = j * 512 + tid;
      int r = u >> 4, c4 = u & 15;
      uint2 w = make_uint2(packbf_rne(pa[j].x, pa[j].y),
                           packbf_rne(pa[j].z, pa[j].w));
      int off = r * 128 + (((c4 >> 1) ^ (r & 7)) << 4) + ((c4 & 1) << 3);
      *reinterpret_cast<uint2*>(ldsA + off) = w;
    }
  };
  auto issueB = [&](int kt) {
#pragma unroll
    for (int j = 0; j < 4; ++j) {
      int W = j * 8 + wave;    // 0..31 chunks of 8 rows
      gload_lds16(gBb + (size_t)W * 4096 + kt * 64, (char*)ldsB + W * 1024);
    }
  };

  f32x4 acc[2][8];
#pragma unroll
  for (int m = 0; m < 2; ++m)
#pragma unroll
    for (int n = 0; n < 8; ++n) acc[m][n] = zero4;

  issueA(0);

  for (int kt = 0; kt < 8; ++kt) {
    __builtin_amdgcn_sched_barrier(0);
    __builtin_amdgcn_s_barrier();        // readers of kt-1 done (reads already
    __builtin_amdgcn_sched_barrier(0);   // drained by each wave's own waits)
    issueB(kt);
    __builtin_amdgcn_sched_barrier(0);   // keep B gloads older than A loads
    writeA();                            // compiler waits pa: vmcnt(4)
    if (kt < 7) {
      issueA(kt + 1);                    // in flight across compute
      __builtin_amdgcn_sched_barrier(0);
      asm volatile("s_waitcnt vmcnt(4) lgkmcnt(0)" ::: "memory");
    } else {
      __builtin_amdgcn_sched_barrier(0);
      asm volatile("s_waitcnt vmcnt(0) lgkmcnt(0)" ::: "memory");
    }
    __builtin_amdgcn_s_barrier();        // tile ready
    __builtin_amdgcn_sched_barrier(0);

#pragma unroll
    for (int ks = 0; ks < 2; ++ks) {
      bf16x8 a0, a1;
      {
        int ar0 = wr * 32 + lrow;
        int ar1 = ar0 + 16;
        a0 = *reinterpret_cast<const bf16x8*>(
            ldsA + ar0 * 128 + (((ks * 4 + lk) ^ (ar0 & 7)) << 4));
        a1 = *reinterpret_cast<const bf16x8*>(
            ldsA + ar1 * 128 + (((ks * 4 + lk) ^ (ar1 & 7)) << 4));
      }
#pragma unroll
      for (int n = 0; n < 8; ++n) {
        int br = wcc * 128 + n * 16 + lrow;
        bf16x8 bv = *reinterpret_cast<const bf16x8*>(
            ldsB + br * 128 + (((ks * 4 + lk) ^ (br & 7)) << 4));
        acc[0][n] = __builtin_amdgcn_mfma_f32_16x16x32_bf16(a0, bv, acc[0][n],
                                                            0, 0, 0);
        acc[1][n] = __builtin_amdgcn_mfma_f32_16x16x32_bf16(a1, bv, acc[1][n],
                                                            0, 0, 0);
      }
    }
  }

  // ---- epilogue: sigmoid(acc + wh_b + cproj) * qt_w, partial over 256 e --
  float asum[2][4];
#pragma unroll
  for (int m = 0; m < 2; ++m)
#pragma unroll
    for (int r = 0; r < 4; ++r) asum[m][r] = 0.f;

#pragma unroll
  for (int n = 0; n < 8; ++n) {
    int e = ncol0 + wcc * 128 + n * 16 + lrow;
    float whb = bias[e];
    float qw = qtw[e];
#pragma unroll
    for (int m = 0; m < 2; ++m)
#pragma unroll
      for (int r = 0; r < 4; ++r) {
        int row = row0 + wr * 32 + m * 16 + lk * 4 + r;
        int bs = ((row / (Hn * Sn)) << 10) | (row & 1023);
        float cp = bf2f(cproj[(size_t)bs * 512 + e]);
        float g = sigmoid_fast(acc[m][n][r] + whb + cp);
        asum[m][r] = fmaf(g, qw, asum[m][r]);
      }
  }
  // reduce over lrow (e within wave)
#pragma unroll
  for (int off = 1; off < 16; off <<= 1)
#pragma unroll
    for (int m = 0; m < 2; ++m)
#pragma unroll
      for (int r = 0; r < 4; ++r)
        asum[m][r] += __shfl_xor(asum[m][r], off, 64);

  if (lrow == 0) {
#pragma unroll
    for (int m = 0; m < 2; ++m)
#pragma unroll
      for (int r = 0; r < 4; ++r)
        red[wcc][wr * 32 + m * 16 + lk * 4 + r] = asum[m][r];
  }
  __syncthreads();
  if (tid < 128)
    part[(size_t)nc * Mall + row0 + tid] = red[0][tid] + red[1][tid];
}

// alpha[i] = part[0][i] + part[1][i] + qt_b
__global__ __launch_bounds__(256) void k_alpha_reduce2(
    const float* __restrict__ part, const float* __restrict__ qtb,
    float* __restrict__ alpha) {
  int i = blockIdx.x * 256 + threadIdx.x;   // 163840 total
  alpha[i] = part[i] + part[(size_t)Mall + i] + qtb[0];
}

// ---------------------------------------------------------------------------
// summed[b,s,:] = sum_h alpha[b,h,s] * hist[b,h,s,:]  (bf16 out)
// ---------------------------------------------------------------------------
__global__ __launch_bounds__(256) void k_summed(
    const float* __restrict__ hist, const float* __restrict__ alpha,
    unsigned short* __restrict__ summed) {
  int idx = blockIdx.x * 256 + threadIdx.x;   // 1048576 = 8192 rows * 128 f4
  int bs = idx >> 7, c4 = idx & 127;
  int b = bs >> 10, s = bs & 1023;
  const float4* hp = reinterpret_cast<const float4*>(hist);
  float4 acc = make_float4(0.f, 0.f, 0.f, 0.f);
#pragma unroll
  for (int h = 0; h < Hn; ++h) {
    int bh = b * Hn + h;
    float a = alpha[(bh << 10) + s];
    float4 v = hp[(size_t)(bh * 1024 + s) * 128 + c4];
    acc.x = fmaf(a, v.x, acc.x);
    acc.y = fmaf(a, v.y, acc.y);
    acc.z = fmaf(a, v.z, acc.z);
    acc.w = fmaf(a, v.w, acc.w);
  }
  ushort4 o;
  o.x = f2bf(acc.x); o.y = f2bf(acc.y); o.z = f2bf(acc.z); o.w = f2bf(acc.w);
  reinterpret_cast<ushort4*>(summed)[idx] = o;
}

// ---------------------------------------------------------------------------
// Kernel: out[8192,256] = [cur | summed] @ wf^T + wf_b   (K=1024)
// ---------------------------------------------------------------------------
__global__ __launch_bounds__(256) void k_final(
    const float* __restrict__ cur,              // [8192][512] fp32
    const unsigned short* __restrict__ summed,  // [8192][512] bf16
    const unsigned short* __restrict__ wfb16,   // [256][1024] bf16
    const float* __restrict__ wf_bias,          // [256]
    float* __restrict__ out) {                  // [8192][256]
  __shared__ __align__(16) unsigned char ldsA[64 * 128];
  __shared__ __align__(16) unsigned char ldsB[128 * 128];
  const int tid = threadIdx.x;
  const int lane = tid & 63, wave = tid >> 6;
  const int lrow = lane & 15, lk = lane >> 4;
  const int row0 = blockIdx.x * 64;
  const int n0 = blockIdx.y * 128;
  const f32x4 zero4 = {0.f, 0.f, 0.f, 0.f};

  f32x4 acc[8];
#pragma unroll
  for (int cf = 0; cf < 8; ++cf) acc[cf] = zero4;

  for (int kt = 0; kt < 16; ++kt) {
    __syncthreads();
#pragma unroll
    for (int slot = 0; slot < 2; ++slot) {
      int idx = (slot * 256 + tid) * 8;
      int row = idx >> 6, k = idx & 63;
      int gcol = kt * 64 + k;
      uint4 p;
      if (kt < 8) {
        const float* src = cur + (size_t)(row0 + row) * 512 + gcol;
        float4 f0 = *reinterpret_cast<const float4*>(src);
        float4 f1 = *reinterpret_cast<const float4*>(src + 4);
        p = pack8_trunc(f0, f1);
      } else {
        p = *reinterpret_cast<const uint4*>(
            summed + (size_t)(row0 + row) * 512 + gcol - 512);
      }
      int off = row * 128 + ((k * 2) ^ ((row & 7) << 4));
      *reinterpret_cast<uint4*>(ldsA + off) = p;
    }
#pragma unroll
    for (int c = 0; c < 4; ++c) {
      int ci = c * 256 + tid;
      int n = ci >> 3, kc = (ci & 7) * 8;
      uint4 p = *reinterpret_cast<const uint4*>(
          wfb16 + (size_t)(n0 + n) * 1024 + kt * 64 + kc);
      int off = n * 128 + ((kc * 2) ^ ((n & 7) << 4));
      *reinterpret_cast<uint4*>(ldsB + off) = p;
    }
    __syncthreads();
#pragma unroll
    for (int ks = 0; ks < 2; ++ks) {
      int kbyte = ks * 64 + lk * 16;
      int ar = wave * 16 + lrow;
      bf16x8 a = *reinterpret_cast<const bf16x8*>(
          ldsA + ar * 128 + (kbyte ^ ((ar & 7) << 4)));
#pragma unroll
      for (int cf = 0; cf < 8; ++cf) {
        int br = cf * 16 + lrow;
        bf16x8 b = *reinterpret_cast<const bf16x8*>(
            ldsB + br * 128 + (kbyte ^ ((br & 7) << 4)));
        acc[cf] = __builtin_amdgcn_mfma_f32_16x16x32_bf16(a, b, acc[cf], 0, 0, 0);
      }
    }
  }
#pragma unroll
  for (int cf = 0; cf < 8; ++cf) {
    int col = n0 + cf * 16 + lrow;
    float bse = wf_bias[col];
#pragma unroll
    for (int r = 0; r < 4; ++r) {
      int row = row0 + wave * 16 + lk * 4 + r;
      out[(size_t)row * 256 + col] = acc[cf][r] + bse;
    }
  }
}

// ===========================================================================
extern "C" void kernel_launch(void* const* d_in, const int* in_sizes, int n_in,
                              void* d_out, int out_size, void* d_ws,
                              size_t ws_size, hipStream_t stream) {
  (void)in_sizes; (void)n_in; (void)out_size;
  const float* hist = (const float*)d_in[0];
  const float* cur  = (const float*)d_in[1];
  const float* wc_w = (const float*)d_in[2];
  const float* wc_b = (const float*)d_in[3];
  const float* wh_w = (const float*)d_in[4];
  const float* wh_b = (const float*)d_in[5];
  const float* qt_w = (const float*)d_in[6];
  const float* qt_b = (const float*)d_in[7];
  const float* wf_w = (const float*)d_in[8];
  const float* wf_b = (const float*)d_in[9];
  float* out = (float*)d_out;
  char* ws = (char*)d_ws;

  unsigned short* wcb    = (unsigned short*)(ws);
  unsigned short* whb    = (unsigned short*)(ws + 524288);
  unsigned short* wfb    = (unsigned short*)(ws + 1048576);
  unsigned short* cproj  = (unsigned short*)(ws + 1572864);   // 8192x512 bf16
  float*          alpha  = (float*)(ws + 9961472);            // 163840 f32
  unsigned short* summed = (unsigned short*)(ws + 10616832);  // 8192x512 bf16
  float*          part   = (float*)(ws + 19005440);           // 2x163840 f32
  const size_t NEED = 19005440 + 1310720;                     // ~20.3 MB

  k_convert_weights<<<dim3(768), dim3(256), 0, stream>>>(wc_w, wh_w, wf_w, wcb,
                                                         whb, wfb);
  k_gemm_bt<0><<<dim3(BS / 128, 4), dim3(256), 0, stream>>>(
      cur, wcb, wc_b, nullptr, nullptr, nullptr, cproj, nullptr);
  if (ws_size >= NEED) {
    k_alpha_p<<<dim3(2560), dim3(512), 0, stream>>>(hist, whb, wh_b, cproj,
                                                    qt_w, part);
    k_alpha_reduce2<<<dim3(640), dim3(256), 0, stream>>>(part, qt_b, alpha);
  } else {
    k_gemm_bt<1><<<dim3(Mall / 128, 1), dim3(256), 0, stream>>>(
        hist, whb, wh_b, cproj, qt_w, qt_b, nullptr, alpha);
  }
  k_summed<<<dim3(4096), dim3(256), 0, stream>>>(hist, alpha, summed);
  k_final<<<dim3(BS / 64, 2), dim3(256), 0, stream>>>(cur, summed, wfb, wf_b,
                                                      out);
}

// Round 5
// 222.958 us; speedup vs baseline: 1.2578x; 1.2578x over previous
//
#include <hip/hip_runtime.h>
#include <hip/hip_bf16.h>
#include <stdint.h>

// Problem constants
static constexpr int Bn = 8, Hn = 20, Sn = 1024, En = 256, D2 = 512, D4 = 1024;
static constexpr int Mall = Bn * Hn * Sn;   // 163840 rows of hist
static constexpr int BS   = Bn * Sn;        // 8192 rows of cur

typedef __attribute__((ext_vector_type(8))) short bf16x8;
typedef __attribute__((ext_vector_type(4))) float f32x4;

__device__ __forceinline__ unsigned short f2bf(float f) {
  unsigned int u = __float_as_uint(f);
  u += 0x7FFFu + ((u >> 16) & 1u);   // RNE
  return (unsigned short)(u >> 16);
}
__device__ __forceinline__ float bf2f(unsigned short u) {
  return __uint_as_float(((unsigned int)u) << 16);
}
__device__ __forceinline__ float sigmoid_fast(float x) {
  return __builtin_amdgcn_rcpf(1.0f + __expf(-x));
}
// pack bf16(lo=a, hi=b) by TRUNCATION in one v_perm_b32
__device__ __forceinline__ unsigned int packbf_trunc(float a, float b) {
  return __builtin_amdgcn_perm(__float_as_uint(b), __float_as_uint(a),
                               0x07060302u);
}
// pack bf16(lo=a, hi=b) with RNE rounding
__device__ __forceinline__ unsigned int packbf_rne(float a, float b) {
  return ((unsigned int)f2bf(b) << 16) | (unsigned int)f2bf(a);
}
__device__ __forceinline__ uint4 pack8_trunc(float4 f0, float4 f1) {
  uint4 p;
  p.x = packbf_trunc(f0.x, f0.y);
  p.y = packbf_trunc(f0.z, f0.w);
  p.z = packbf_trunc(f1.x, f1.y);
  p.w = packbf_trunc(f1.z, f1.w);
  return p;
}

typedef const __attribute__((address_space(1))) void gv_t;
typedef __attribute__((address_space(3))) void lv_t;
__device__ __forceinline__ void gload_lds16(const void* g, void* l) {
  __builtin_amdgcn_global_load_lds((gv_t*)g, (lv_t*)l, 16, 0, 0);
}

// ---------------------------------------------------------------------------
// Kernel: convert the three weight matrices fp32 -> bf16 (each 262144 el)
// ---------------------------------------------------------------------------
__global__ __launch_bounds__(256) void k_convert_weights(
    const float* __restrict__ wc, const float* __restrict__ wh,
    const float* __restrict__ wf,
    unsigned short* __restrict__ wcb, unsigned short* __restrict__ whb,
    unsigned short* __restrict__ wfb) {
  int idx4 = blockIdx.x * 256 + threadIdx.x;      // 0..196607 (x4 elements)
  int a = idx4 >> 16;                             // which array (65536 float4 each)
  int r = idx4 & 65535;
  const float* s = (a == 0) ? wc : (a == 1) ? wh : wf;
  unsigned short* d = (a == 0) ? wcb : (a == 1) ? whb : wfb;
  float4 v = reinterpret_cast<const float4*>(s)[r];
  ushort4 o;
  o.x = f2bf(v.x); o.y = f2bf(v.y); o.z = f2bf(v.z); o.w = f2bf(v.w);
  reinterpret_cast<ushort4*>(d)[r] = o;
}

// ---------------------------------------------------------------------------
// GEMM (B^T form): C[M,512] = A[M,512] (fp32, trunc->bf16) * W[512,512]^T
// MODE 0: epilogue writes c_proj bf16 (+bias). grid=(Mtiles, 4 Nchunks)
// MODE 1 (fallback only): alpha in one kernel, nc looped inside.
// ---------------------------------------------------------------------------
template <int MODE>
__global__ __launch_bounds__(256) void k_gemm_bt(
    const float* __restrict__ A,               // [M][512] fp32
    const unsigned short* __restrict__ Bw,     // [512][512] bf16 (N-major)
    const float* __restrict__ bias,            // [512] fp32 (wc_b / wh_b)
    const unsigned short* __restrict__ cproj,  // MODE1: [8192][512] bf16
    const float* __restrict__ qtw,             // MODE1: [512] fp32
    const float* __restrict__ qtb,             // MODE1: [1] fp32
    unsigned short* __restrict__ cproj_out,    // MODE0 output
    float* __restrict__ alpha_out) {           // MODE1 output [163840]
  __shared__ __align__(16) unsigned char ldsA[128 * 128];
  __shared__ __align__(16) unsigned char ldsB[128 * 128];

  const int tid = threadIdx.x;
  const int lane = tid & 63, wave = tid >> 6;
  const int lrow = lane & 15, lk = lane >> 4;
  const int row0 = blockIdx.x * 128;
  const f32x4 zero4 = {0.f, 0.f, 0.f, 0.f};

  float asum[2][4];
  if (MODE == 1) {
#pragma unroll
    for (int rf = 0; rf < 2; ++rf)
#pragma unroll
      for (int r = 0; r < 4; ++r) asum[rf][r] = 0.f;
  }

  const int nc_begin = (MODE == 0) ? blockIdx.y : 0;
  const int nc_end   = (MODE == 0) ? (int)blockIdx.y + 1 : 4;

  for (int nc = nc_begin; nc < nc_end; ++nc) {
    f32x4 acc[2][8];
#pragma unroll
    for (int rf = 0; rf < 2; ++rf)
#pragma unroll
      for (int cf = 0; cf < 8; ++cf) acc[rf][cf] = zero4;

    for (int kt = 0; kt < 8; ++kt) {
      __syncthreads();
#pragma unroll
      for (int slot = 0; slot < 4; ++slot) {
        int idx = (slot * 256 + tid) * 8;
        int row = idx >> 6, k = idx & 63;
        const float* src = A + (size_t)(row0 + row) * 512 + kt * 64 + k;
        float4 f0 = *reinterpret_cast<const float4*>(src);
        float4 f1 = *reinterpret_cast<const float4*>(src + 4);
        uint4 p = pack8_trunc(f0, f1);
        int off = row * 128 + ((k * 2) ^ ((row & 7) << 4));
        *reinterpret_cast<uint4*>(ldsA + off) = p;
      }
#pragma unroll
      for (int c = 0; c < 4; ++c) {
        int ci = c * 256 + tid;
        int n = ci >> 3, kc = (ci & 7) * 8;
        const unsigned short* src =
            Bw + (size_t)(nc * 128 + n) * 512 + kt * 64 + kc;
        uint4 p = *reinterpret_cast<const uint4*>(src);
        int off = n * 128 + ((kc * 2) ^ ((n & 7) << 4));
        *reinterpret_cast<uint4*>(ldsB + off) = p;
      }
      __syncthreads();
#pragma unroll
      for (int ks = 0; ks < 2; ++ks) {
        int kbyte = ks * 64 + lk * 16;
        bf16x8 af[2];
#pragma unroll
        for (int rf = 0; rf < 2; ++rf) {
          int ar = wave * 32 + rf * 16 + lrow;
          af[rf] = *reinterpret_cast<const bf16x8*>(
              ldsA + ar * 128 + (kbyte ^ ((ar & 7) << 4)));
        }
#pragma unroll
        for (int cf = 0; cf < 8; ++cf) {
          int br = cf * 16 + lrow;
          bf16x8 bf = *reinterpret_cast<const bf16x8*>(
              ldsB + br * 128 + (kbyte ^ ((br & 7) << 4)));
#pragma unroll
          for (int rf = 0; rf < 2; ++rf)
            acc[rf][cf] = __builtin_amdgcn_mfma_f32_16x16x32_bf16(
                af[rf], bf, acc[rf][cf], 0, 0, 0);
        }
      }
    }

    if (MODE == 0) {
#pragma unroll
      for (int cf = 0; cf < 8; ++cf) {
        int e = nc * 128 + cf * 16 + lrow;
        float bse = bias[e];
#pragma unroll
        for (int rf = 0; rf < 2; ++rf)
#pragma unroll
          for (int r = 0; r < 4; ++r) {
            int row = row0 + wave * 32 + rf * 16 + lk * 4 + r;
            cproj_out[(size_t)row * 512 + e] = f2bf(acc[rf][cf][r] + bse);
          }
      }
    } else {
#pragma unroll
      for (int cf = 0; cf < 8; ++cf) {
        int e = nc * 128 + cf * 16 + lrow;
        float whb = bias[e];
        float qw = qtw[e];
#pragma unroll
        for (int rf = 0; rf < 2; ++rf)
#pragma unroll
          for (int r = 0; r < 4; ++r) {
            int row = row0 + wave * 32 + rf * 16 + lk * 4 + r;
            int bsrow = ((row / (Hn * Sn)) << 10) | (row & 1023);
            float cp = bf2f(cproj[(size_t)bsrow * 512 + e]);
            float g = sigmoid_fast(acc[rf][cf][r] + whb + cp);
            asum[rf][r] = fmaf(g, qw, asum[rf][r]);
          }
      }
    }
  }

  if (MODE == 1) {
#pragma unroll
    for (int off = 1; off < 16; off <<= 1) {
#pragma unroll
      for (int rf = 0; rf < 2; ++rf)
#pragma unroll
        for (int r = 0; r < 4; ++r)
          asum[rf][r] += __shfl_xor(asum[rf][r], off, 64);
    }
    if (lrow == 0) {
      float qb = qtb[0];
#pragma unroll
      for (int rf = 0; rf < 2; ++rf)
#pragma unroll
        for (int r = 0; r < 4; ++r) {
          int row = row0 + wave * 32 + rf * 16 + lk * 4 + r;
          alpha_out[row] = asum[rf][r] + qb;
        }
    }
  }
}

// ---------------------------------------------------------------------------
// k_alpha_summed: FUSED hist pass, BARRIER-FREE K-loop. One block per
// (b, 4 s). 512 thr. A (80x512 bf16, 80KB) staged ENTIRELY in the prologue
// (pipelined reg-pack; the 160KB fp32 burst saturates the CU's HBM share).
// B staging is WAVE-PRIVATE: wave w loads exactly its own 64 e-rows
// (4 gload_lds per BK=32 kstep, dbuf, issued 2 ksteps ahead, self-timed
// with own vmcnt(4) -- NO barriers in the 16-kstep loop; waves free-run
// and anti-phase on the SIMDs (m114 overlap). One __syncthreads total
// before the loop; two after for the ldsB->red alias.
// ---------------------------------------------------------------------------
__global__ __launch_bounds__(512, 2) void k_alpha_summed(
    const float* __restrict__ A,               // hist [163840][512] fp32
    const unsigned short* __restrict__ Bw,     // whb [512][512] bf16
    const float* __restrict__ bias,            // wh_b [512]
    const unsigned short* __restrict__ cproj,  // [8192][512] bf16
    const float* __restrict__ qtw,             // [512]
    const float* __restrict__ qtb,             // [1]
    unsigned short* __restrict__ summed) {     // [8192][512] bf16
  __shared__ __align__(16) unsigned char ldsA[81920];  // bf16 80x512 swizzled
  __shared__ __align__(16) unsigned char ldsB[65536];  // 2 x 8waves x 4KB
  __shared__ __align__(16) unsigned char ldsC[4096];   // cproj 4x512 bf16

  const int tid = threadIdx.x;
  const int lane = tid & 63, wave = tid >> 6;
  const int lrow = lane & 15, lk = lane >> 4;
  const int wc = wave;                        // 8 waves own 8 e-eighths
  const int b = blockIdx.x >> 8;
  const int s0 = (blockIdx.x & 255) * 4;
  const size_t rowbase = (size_t)b * 20480;
  const f32x4 zero4 = {0.f, 0.f, 0.f, 0.f};

  // ---- B wave-private source base. Wave w consumes B rows [64w,64w+64).
  // instr j covers local rows j*16+(lane>>2), slot s=lane&3 holds global
  // 16B-chunk g = s ^ ((rl>>1)&3); with rl=j*16+(lane>>2) the key is
  // (lane>>3)&3 (j-invariant). ds_read: 2 lanes/bank-quad = free (m136).
  const unsigned short* gB0 =
      Bw + (size_t)(wave * 64 + (lane >> 2)) * 512 +
      ((lane & 3) ^ ((lane >> 3) & 3)) * 8;

  auto issueB = [&](int k) {
#pragma unroll
    for (int j = 0; j < 4; ++j)
      gload_lds16(gB0 + (size_t)j * 8192 + k * 32,
                  (char*)ldsB + (k & 1) * 32768 + wave * 4096 + j * 1024);
  };

  // ---- A prologue staging: 10240 float4 units, 20/thread in 4 batches ----
  float4 pa0[5], pa1[5];
  auto issueA = [&](int bt, float4 (&pa)[5]) {
#pragma unroll
    for (int j = 0; j < 5; ++j) {
      int u = (bt * 5 + j) * 512 + tid;
      int mr = u >> 7, c4 = u & 127;
      pa[j] = *reinterpret_cast<const float4*>(
          A + (rowbase + (size_t)(mr >> 2) * 1024 + s0 + (mr & 3)) * 512 +
          c4 * 4);
    }
  };
  auto writeA = [&](int bt, float4 (&pa)[5]) {
#pragma unroll
    for (int j = 0; j < 5; ++j) {
      int u = (bt * 5 + j) * 512 + tid;
      int mr = u >> 7, c4 = u & 127;
      unsigned int u0 = packbf_rne(pa[j].x, pa[j].y);
      unsigned int u1 = packbf_rne(pa[j].z, pa[j].w);
      int off = mr * 1024 + (((c4 >> 1) ^ (mr & 7)) << 4) + ((c4 & 1) << 3);
      *reinterpret_cast<uint2*>(ldsA + off) = make_uint2(u0, u1);
    }
  };

  // ---- prologue ----
  if (wave < 4) {  // cproj tile: 4 rows x 512 bf16 = 4KB, linear
    const unsigned short* csrc = cproj + ((size_t)b * 1024 + s0) * 512;
    gload_lds16(csrc + tid * 8, (char*)ldsC + wave * 1024);
  }
  issueA(0, pa0);
  issueA(1, pa1);
  writeA(0, pa0);
  issueA(2, pa0);
  writeA(1, pa1);
  issueA(3, pa1);
  writeA(2, pa0);
  writeA(3, pa1);
  issueB(0);
  issueB(1);
  __syncthreads();   // single full drain: A tile + cproj + B(0),B(1) ready

  f32x4 acc[5][4];
#pragma unroll
  for (int tm = 0; tm < 5; ++tm)
#pragma unroll
    for (int n = 0; n < 4; ++n) acc[tm][n] = zero4;

  // ---- barrier-free K-loop: 16 ksteps of BK=32, self-timed per wave ----
#pragma unroll 4
  for (int k = 0; k < 16; ++k) {
    bf16x8 af[5];
#pragma unroll
    for (int tm = 0; tm < 5; ++tm) {
      int r = tm * 16 + lrow;
      int g = (k * 4 + lk) ^ (r & 7);
      af[tm] = *reinterpret_cast<const bf16x8*>(ldsA + r * 1024 + g * 16);
    }
    const unsigned char* bbase = ldsB + (k & 1) * 32768 + wave * 4096;
#pragma unroll
    for (int n = 0; n < 4; ++n) {
      int rl = n * 16 + lrow;
      int slot = lk ^ ((rl >> 1) & 3);
      bf16x8 bv = *reinterpret_cast<const bf16x8*>(bbase + rl * 64 + slot * 16);
#pragma unroll
      for (int tm = 0; tm < 5; ++tm)
        acc[tm][n] = __builtin_amdgcn_mfma_f32_16x16x32_bf16(af[tm], bv,
                                                             acc[tm][n], 0, 0,
                                                             0);
    }
    // all this wave's B-buf reads retired before overwriting the buffer
    asm volatile("s_waitcnt lgkmcnt(0)" ::: "memory");
    __builtin_amdgcn_sched_barrier(0);
    if (k < 14) {
      issueB(k + 2);
      __builtin_amdgcn_sched_barrier(0);
      asm volatile("s_waitcnt vmcnt(4)" ::: "memory");  // B(k+1) landed
    } else if (k == 14) {
      asm volatile("s_waitcnt vmcnt(0)" ::: "memory");  // B(15) landed
    }
    __builtin_amdgcn_sched_barrier(0);
  }

  // ---- phase 1: alpha partials. e = wc*64 + n*16 + lrow; si = r ----
  float asum[5][4];
#pragma unroll
  for (int tm = 0; tm < 5; ++tm)
#pragma unroll
    for (int r = 0; r < 4; ++r) asum[tm][r] = 0.f;

  const unsigned short* cpl = reinterpret_cast<const unsigned short*>(ldsC);
#pragma unroll
  for (int n = 0; n < 4; ++n) {
    int e = wc * 64 + n * 16 + lrow;
    float whb = bias[e];
    float qw = qtw[e];
    float cpv[4];
#pragma unroll
    for (int si = 0; si < 4; ++si) cpv[si] = bf2f(cpl[si * 512 + e]);
#pragma unroll
    for (int tm = 0; tm < 5; ++tm)
#pragma unroll
      for (int r = 0; r < 4; ++r) {
        float g = sigmoid_fast(acc[tm][n][r] + whb + cpv[r]);
        asum[tm][r] = fmaf(g, qw, asum[tm][r]);
      }
  }
  // reduce across lrow (16 lanes)
#pragma unroll
  for (int off = 1; off < 16; off <<= 1)
#pragma unroll
    for (int tm = 0; tm < 5; ++tm)
#pragma unroll
      for (int r = 0; r < 4; ++r)
        asum[tm][r] += __shfl_xor(asum[tm][r], off, 64);

  __syncthreads();  // ALL waves out of the K-loop before aliasing ldsB
  float* red = reinterpret_cast<float*>(ldsB);  // [8 wc][80 rows]
  if (lrow == 0) {
#pragma unroll
    for (int tm = 0; tm < 5; ++tm)
#pragma unroll
      for (int r = 0; r < 4; ++r)
        red[wc * 80 + tm * 16 + lk * 4 + r] = asum[tm][r];
  }
  __syncthreads();

  // ---- phase 2: summed[b, s0+si, :] = sum_h alpha[h*4+si] * hist_lds ----
  if (wave < 4) {
    const int si = wave;
    const float qb = qtb[0];
    float o[8];
#pragma unroll
    for (int j = 0; j < 8; ++j) o[j] = 0.f;
#pragma unroll
    for (int h = 0; h < 20; ++h) {
      int mr = h * 4 + si;
      float a = qb;
#pragma unroll
      for (int wq = 0; wq < 8; ++wq) a += red[wq * 80 + mr];
      int g = lane ^ (mr & 7);
      bf16x8 av = *reinterpret_cast<const bf16x8*>(ldsA + mr * 1024 + g * 16);
#pragma unroll
      for (int j = 0; j < 8; ++j)
        o[j] = fmaf(a, bf2f((unsigned short)av[j]), o[j]);
    }
    uint4 pk;
    pk.x = packbf_rne(o[0], o[1]);
    pk.y = packbf_rne(o[2], o[3]);
    pk.z = packbf_rne(o[4], o[5]);
    pk.w = packbf_rne(o[6], o[7]);
    size_t orow = (size_t)b * 1024 + s0 + si;
    reinterpret_cast<uint4*>(summed)[orow * 64 + lane] = pk;
  }
}

// ---------------------------------------------------------------------------
// summed[b,s,:] = sum_h alpha[b,h,s] * hist[b,h,s,:]  (bf16 out) — FALLBACK
// ---------------------------------------------------------------------------
__global__ __launch_bounds__(256) void k_summed(
    const float* __restrict__ hist, const float* __restrict__ alpha,
    unsigned short* __restrict__ summed) {
  int idx = blockIdx.x * 256 + threadIdx.x;   // 1048576 = 8192 rows * 128 f4
  int bs = idx >> 7, c4 = idx & 127;
  int b = bs >> 10, s = bs & 1023;
  const float4* hp = reinterpret_cast<const float4*>(hist);
  float4 acc = make_float4(0.f, 0.f, 0.f, 0.f);
#pragma unroll
  for (int h = 0; h < Hn; ++h) {
    int bh = b * Hn + h;
    float a = alpha[(bh << 10) + s];
    float4 v = hp[(size_t)(bh * 1024 + s) * 128 + c4];
    acc.x = fmaf(a, v.x, acc.x);
    acc.y = fmaf(a, v.y, acc.y);
    acc.z = fmaf(a, v.z, acc.z);
    acc.w = fmaf(a, v.w, acc.w);
  }
  ushort4 o;
  o.x = f2bf(acc.x); o.y = f2bf(acc.y); o.z = f2bf(acc.z); o.w = f2bf(acc.w);
  reinterpret_cast<ushort4*>(summed)[idx] = o;
}

// ---------------------------------------------------------------------------
// Kernel: out[8192,256] = [cur | summed] @ wf^T + wf_b   (K=1024)
// ---------------------------------------------------------------------------
__global__ __launch_bounds__(256) void k_final(
    const float* __restrict__ cur,              // [8192][512] fp32
    const unsigned short* __restrict__ summed,  // [8192][512] bf16
    const unsigned short* __restrict__ wfb16,   // [256][1024] bf16
    const float* __restrict__ wf_bias,          // [256]
    float* __restrict__ out) {                  // [8192][256]
  __shared__ __align__(16) unsigned char ldsA[64 * 128];
  __shared__ __align__(16) unsigned char ldsB[128 * 128];
  const int tid = threadIdx.x;
  const int lane = tid & 63, wave = tid >> 6;
  const int lrow = lane & 15, lk = lane >> 4;
  const int row0 = blockIdx.x * 64;
  const int n0 = blockIdx.y * 128;
  const f32x4 zero4 = {0.f, 0.f, 0.f, 0.f};

  f32x4 acc[8];
#pragma unroll
  for (int cf = 0; cf < 8; ++cf) acc[cf] = zero4;

  for (int kt = 0; kt < 16; ++kt) {
    __syncthreads();
#pragma unroll
    for (int slot = 0; slot < 2; ++slot) {
      int idx = (slot * 256 + tid) * 8;
      int row = idx >> 6, k = idx & 63;
      int gcol = kt * 64 + k;
      uint4 p;
      if (kt < 8) {
        const float* src = cur + (size_t)(row0 + row) * 512 + gcol;
        float4 f0 = *reinterpret_cast<const float4*>(src);
        float4 f1 = *reinterpret_cast<const float4*>(src + 4);
        p = pack8_trunc(f0, f1);
      } else {
        p = *reinterpret_cast<const uint4*>(
            summed + (size_t)(row0 + row) * 512 + gcol - 512);
      }
      int off = row * 128 + ((k * 2) ^ ((row & 7) << 4));
      *reinterpret_cast<uint4*>(ldsA + off) = p;
    }
#pragma unroll
    for (int c = 0; c < 4; ++c) {
      int ci = c * 256 + tid;
      int n = ci >> 3, kc = (ci & 7) * 8;
      uint4 p = *reinterpret_cast<const uint4*>(
          wfb16 + (size_t)(n0 + n) * 1024 + kt * 64 + kc);
      int off = n * 128 + ((kc * 2) ^ ((n & 7) << 4));
      *reinterpret_cast<uint4*>(ldsB + off) = p;
    }
    __syncthreads();
#pragma unroll
    for (int ks = 0; ks < 2; ++ks) {
      int kbyte = ks * 64 + lk * 16;
      int ar = wave * 16 + lrow;
      bf16x8 a = *reinterpret_cast<const bf16x8*>(
          ldsA + ar * 128 + (kbyte ^ ((ar & 7) << 4)));
#pragma unroll
      for (int cf = 0; cf < 8; ++cf) {
        int br = cf * 16 + lrow;
        bf16x8 b = *reinterpret_cast<const bf16x8*>(
            ldsB + br * 128 + (kbyte ^ ((br & 7) << 4)));
        acc[cf] = __builtin_amdgcn_mfma_f32_16x16x32_bf16(a, b, acc[cf], 0, 0, 0);
      }
    }
  }
#pragma unroll
  for (int cf = 0; cf < 8; ++cf) {
    int col = n0 + cf * 16 + lrow;
    float bse = wf_bias[col];
#pragma unroll
    for (int r = 0; r < 4; ++r) {
      int row = row0 + wave * 16 + lk * 4 + r;
      out[(size_t)row * 256 + col] = acc[cf][r] + bse;
    }
  }
}

// ===========================================================================
extern "C" void kernel_launch(void* const* d_in, const int* in_sizes, int n_in,
                              void* d_out, int out_size, void* d_ws,
                              size_t ws_size, hipStream_t stream) {
  (void)in_sizes; (void)n_in; (void)out_size;
  const float* hist = (const float*)d_in[0];
  const float* cur  = (const float*)d_in[1];
  const float* wc_w = (const float*)d_in[2];
  const float* wc_b = (const float*)d_in[3];
  const float* wh_w = (const float*)d_in[4];
  const float* wh_b = (const float*)d_in[5];
  const float* qt_w = (const float*)d_in[6];
  const float* qt_b = (const float*)d_in[7];
  const float* wf_w = (const float*)d_in[8];
  const float* wf_b = (const float*)d_in[9];
  float* out = (float*)d_out;
  char* ws = (char*)d_ws;

  unsigned short* wcb    = (unsigned short*)(ws);
  unsigned short* whb    = (unsigned short*)(ws + 524288);
  unsigned short* wfb    = (unsigned short*)(ws + 1048576);
  unsigned short* cproj  = (unsigned short*)(ws + 1572864);   // 8192x512 bf16
  float*          alpha  = (float*)(ws + 9961472);            // fallback only
  unsigned short* summed = (unsigned short*)(ws + 10616832);  // 8192x512 bf16
  const size_t NEED = 19005440;                               // ~18.1 MB

  k_convert_weights<<<dim3(768), dim3(256), 0, stream>>>(wc_w, wh_w, wf_w, wcb,
                                                         whb, wfb);
  k_gemm_bt<0><<<dim3(BS / 128, 4), dim3(256), 0, stream>>>(
      cur, wcb, wc_b, nullptr, nullptr, nullptr, cproj, nullptr);
  if (ws_size >= NEED) {
    k_alpha_summed<<<dim3(2048), dim3(512), 0, stream>>>(
        hist, whb, wh_b, cproj, qt_w, qt_b, summed);
  } else {
    k_gemm_bt<1><<<dim3(Mall / 128, 1), dim3(256), 0, stream>>>(
        hist, whb, wh_b, cproj, qt_w, qt_b, nullptr, alpha);
    k_summed<<<dim3(4096), dim3(256), 0, stream>>>(hist, alpha, summed);
  }
  k_final<<<dim3(BS / 64, 2), dim3(256), 0, stream>>>(cur, summed, wfb, wf_b,
                                                      out);
}